// Round 1
// baseline (370.685 us; speedup 1.0000x reference)
//
#include <hip/hip_runtime.h>
#include <hip/hip_bf16.h>

// ---------------------------------------------------------------------------
// GCN: h = BN(tanh-pre) of GraphConv1(x) ; out = GraphConv2(tanh(BN(h)))
// GraphConv(x) = segment_sum(w_e * x[src] -> dst) @ W_rel + b + x @ W_root
// Key restructure: matmul and segment_sum commute (both linear), so layer 2
// computes y2 = h_act @ W2_rel FIRST (N x 32), then scatters 32 floats/edge.
// ---------------------------------------------------------------------------

__device__ __forceinline__ void atomAdd(float* p, float v) {
    unsafeAtomicAdd(p, v);
}

// Detect whether edge_index is int64 or int32 (harness dtype ambiguity).
// Reading int32 data as int64 merges two random values in [0,5e4): the high
// word is nonzero with prob 1-2e-5 per element -> value >= 2^32 >> N.
__global__ void detect64_k(const void* __restrict__ ei, int E, int N, int* flag) {
    __shared__ int ok;
    if (threadIdx.x == 0) ok = 1;
    __syncthreads();
    const long long* p = (const long long*)ei;
    int cnt = (E < 1024) ? E : 1024;
    for (int i = threadIdx.x; i < cnt; i += blockDim.x) {
        long long v = p[i];
        if (v < 0 || v >= (long long)N) ok = 0;  // benign race
    }
    __syncthreads();
    if (threadIdx.x == 0) *flag = ok;
}

// Layer-1 aggregation: agg[dst][f] += w_e * x[src][f], F=64, one edge/wave.
__global__ __launch_bounds__(256) void scatter1_k(
    const float* __restrict__ x, const float* __restrict__ ea,
    const void* __restrict__ ei, const int* __restrict__ flag,
    float* __restrict__ agg, int E) {
    const bool is64 = (*flag != 0);
    const int lane = threadIdx.x & 63;
    long long wid = ((long long)blockIdx.x * blockDim.x + threadIdx.x) >> 6;
    long long nw  = ((long long)gridDim.x * blockDim.x) >> 6;
    const int* p32 = (const int*)ei;
    const long long* p64 = (const long long*)ei;
    for (long long e = wid; e < E; e += nw) {
        int src, dst;
        if (is64) { src = (int)p64[e]; dst = (int)p64[E + e]; }
        else      { src = p32[e];      dst = p32[E + e]; }
        float w = ea[e];
        float v = w * x[src * 64 + lane];
        atomAdd(&agg[dst * 64 + lane], v);
    }
}

// h = [agg | x] @ [W1_rel ; W1_root] + b1  (K = 64+64 = 128, Ncols = 128)
// Fused epilogue: per-block column sum / sumsq partials -> global atomics.
__global__ __launch_bounds__(256) void gemm1_k(
    const float* __restrict__ agg, const float* __restrict__ x,
    const float* __restrict__ W1rel, const float* __restrict__ W1root,
    const float* __restrict__ b1, float* __restrict__ h,
    float* __restrict__ bnsum, float* __restrict__ bnsq, int N) {
    __shared__ float As[32][128];
    __shared__ float redS[4][128];
    __shared__ float redQ[4][128];
    const int t = threadIdx.x;
    const int row0 = blockIdx.x * 32;

    // Stage A = [agg row (64) | x row (64)] for 32 rows.
    for (int i = t; i < 32 * 32; i += 256) {
        int r = i >> 5, q = i & 31;
        int rr = row0 + r;
        float4 v = make_float4(0.f, 0.f, 0.f, 0.f);
        if (rr < N) {
            if (q < 16) v = ((const float4*)(agg + (size_t)rr * 64))[q];
            else        v = ((const float4*)(x   + (size_t)rr * 64))[q - 16];
        }
        ((float4*)As[r])[q] = v;
    }
    __syncthreads();

    const int c2 = (t & 63) * 2;   // two output cols per thread
    const int rg = t >> 6;         // wave id: rows rg*8 .. rg*8+7
    float acc[8][2];
#pragma unroll
    for (int r = 0; r < 8; r++) { acc[r][0] = 0.f; acc[r][1] = 0.f; }

#pragma unroll
    for (int half = 0; half < 2; half++) {
        const float* W = half ? W1root : W1rel;  // [64][128]
        const int kbase = half * 64;
        for (int kk = 0; kk < 64; kk += 4) {
            float2 wa = *(const float2*)(W + (kk + 0) * 128 + c2);
            float2 wb = *(const float2*)(W + (kk + 1) * 128 + c2);
            float2 wc = *(const float2*)(W + (kk + 2) * 128 + c2);
            float2 wd = *(const float2*)(W + (kk + 3) * 128 + c2);
#pragma unroll
            for (int r = 0; r < 8; r++) {
                const float4 a = *(const float4*)&As[rg * 8 + r][kbase + kk];
                acc[r][0] = fmaf(a.x, wa.x, fmaf(a.y, wb.x, fmaf(a.z, wc.x, fmaf(a.w, wd.x, acc[r][0]))));
                acc[r][1] = fmaf(a.x, wa.y, fmaf(a.y, wb.y, fmaf(a.z, wc.y, fmaf(a.w, wd.y, acc[r][1]))));
            }
        }
    }

    float bc0 = b1[c2], bc1 = b1[c2 + 1];
    float s0 = 0.f, s1 = 0.f, q0 = 0.f, q1 = 0.f;
#pragma unroll
    for (int r = 0; r < 8; r++) {
        int rr = row0 + rg * 8 + r;
        if (rr < N) {
            float v0 = acc[r][0] + bc0;
            float v1 = acc[r][1] + bc1;
            *(float2*)(h + (size_t)rr * 128 + c2) = make_float2(v0, v1);
            s0 += v0; s1 += v1; q0 += v0 * v0; q1 += v1 * v1;
        }
    }
    redS[rg][c2] = s0; redS[rg][c2 + 1] = s1;
    redQ[rg][c2] = q0; redQ[rg][c2 + 1] = q1;
    __syncthreads();
    if (t < 128) {
        float s = redS[0][t] + redS[1][t] + redS[2][t] + redS[3][t];
        float q = redQ[0][t] + redQ[1][t] + redQ[2][t] + redQ[3][t];
        atomAdd(&bnsum[t], s);
        atomAdd(&bnsq[t], q);
    }
}

__global__ void bnfinal_k(const float* __restrict__ bnsum, const float* __restrict__ bnsq,
                          const float* __restrict__ gamma, const float* __restrict__ beta,
                          float* __restrict__ scale, float* __restrict__ shift, int N) {
    int i = threadIdx.x;  // 128 threads
    float inv = 1.0f / (float)N;
    float mean = bnsum[i] * inv;
    float var = bnsq[i] * inv - mean * mean;
    if (var < 0.f) var = 0.f;
    float sc = gamma[i] * rsqrtf(var + 1e-5f);
    scale[i] = sc;
    shift[i] = beta[i] - mean * sc;
}

// a = tanh(h*scale + shift) applied at staging; computes
//   y2  = a @ W2_rel          (ws, feeds scatter2)
//   out = a @ W2_root + b2    (d_out, scatter2 accumulates on top)
__global__ __launch_bounds__(256) void gemm2_k(
    const float* __restrict__ h, const float* __restrict__ scale,
    const float* __restrict__ shift, const float* __restrict__ W2rel,
    const float* __restrict__ W2root, const float* __restrict__ b2,
    float* __restrict__ y2, float* __restrict__ out, int N) {
    __shared__ float As[32][128];
    const int t = threadIdx.x;
    const int row0 = blockIdx.x * 32;

    for (int i = t; i < 32 * 32; i += 256) {
        int r = i >> 5, q = i & 31;
        int rr = row0 + r;
        float4 v = make_float4(0.f, 0.f, 0.f, 0.f);
        if (rr < N) {
            float4 hv = ((const float4*)(h + (size_t)rr * 128))[q];
            float4 sc = ((const float4*)scale)[q];
            float4 sh = ((const float4*)shift)[q];
            v.x = tanhf(fmaf(hv.x, sc.x, sh.x));
            v.y = tanhf(fmaf(hv.y, sc.y, sh.y));
            v.z = tanhf(fmaf(hv.z, sc.z, sh.z));
            v.w = tanhf(fmaf(hv.w, sc.w, sh.w));
        }
        ((float4*)As[r])[q] = v;
    }
    __syncthreads();

    const int c = t & 63;
    const int rg = t >> 6;
    const bool isRel = (c < 32);
    const float* W = isRel ? W2rel : W2root;   // [128][32]
    const int cc = isRel ? c : (c - 32);
    float acc[8];
#pragma unroll
    for (int r = 0; r < 8; r++) acc[r] = 0.f;

    for (int k = 0; k < 128; k += 4) {
        float wa = W[(k + 0) * 32 + cc];
        float wb = W[(k + 1) * 32 + cc];
        float wc = W[(k + 2) * 32 + cc];
        float wd = W[(k + 3) * 32 + cc];
#pragma unroll
        for (int r = 0; r < 8; r++) {
            const float4 a = *(const float4*)&As[rg * 8 + r][k];
            acc[r] = fmaf(a.x, wa, fmaf(a.y, wb, fmaf(a.z, wc, fmaf(a.w, wd, acc[r]))));
        }
    }

#pragma unroll
    for (int r = 0; r < 8; r++) {
        int rr = row0 + rg * 8 + r;
        if (rr < N) {
            if (isRel) y2[(size_t)rr * 32 + cc] = acc[r];
            else       out[(size_t)rr * 32 + cc] = acc[r] + b2[cc];
        }
    }
}

// Layer-2 aggregation into d_out: out[dst][f] += w_e * y2[src][f], F=32,
// two edges per wave (lanes 0-31 / 32-63).
__global__ __launch_bounds__(256) void scatter2_k(
    const float* __restrict__ y2, const float* __restrict__ ea,
    const void* __restrict__ ei, const int* __restrict__ flag,
    float* __restrict__ out, int E) {
    const bool is64 = (*flag != 0);
    const int lane = threadIdx.x & 63;
    const int sub = lane >> 5;
    const int f = lane & 31;
    long long wid = ((long long)blockIdx.x * blockDim.x + threadIdx.x) >> 6;
    long long nw  = ((long long)gridDim.x * blockDim.x) >> 6;
    const int* p32 = (const int*)ei;
    const long long* p64 = (const long long*)ei;
    for (long long base = wid * 2; base < E; base += nw * 2) {
        long long e = base + sub;
        if (e < E) {
            int src, dst;
            if (is64) { src = (int)p64[e]; dst = (int)p64[E + e]; }
            else      { src = p32[e];      dst = p32[E + e]; }
            float w = ea[e];
            atomAdd(&out[dst * 32 + f], w * y2[src * 32 + f]);
        }
    }
}

extern "C" void kernel_launch(void* const* d_in, const int* in_sizes, int n_in,
                              void* d_out, int out_size, void* d_ws, size_t ws_size,
                              hipStream_t stream) {
    const float* x      = (const float*)d_in[0];
    const float* ea     = (const float*)d_in[1];
    const float* W1rel  = (const float*)d_in[2];
    const float* b1     = (const float*)d_in[3];
    const float* W1root = (const float*)d_in[4];
    const float* gamma  = (const float*)d_in[5];
    const float* beta   = (const float*)d_in[6];
    const float* W2rel  = (const float*)d_in[7];
    const float* b2     = (const float*)d_in[8];
    const float* W2root = (const float*)d_in[9];
    const void*  ei     = d_in[10];

    const int N = in_sizes[0] / 64;   // 50000
    const int E = in_sizes[1];        // 800000

    char* ws = (char*)d_ws;
    size_t off = 0;
    float* agg1    = (float*)(ws + off); off += (size_t)N * 64 * 4;   // 12.8 MB
    float* bnsum   = (float*)(ws + off); off += 512;
    float* bnsq    = (float*)(ws + off); off += 512;
    const size_t zeroBytes = off;                                     // memset range
    float* bnscale = (float*)(ws + off); off += 512;
    float* bnshift = (float*)(ws + off); off += 512;
    int*   flag    = (int*)  (ws + off); off += 256;
    float* h       = (float*)(ws + off); off += (size_t)N * 128 * 4;  // 25.6 MB
    float* y2      = (float*)(ws + off); off += (size_t)N * 32 * 4;   // 6.4 MB

    hipMemsetAsync(agg1, 0, zeroBytes, stream);
    detect64_k<<<1, 256, 0, stream>>>(ei, E, N, flag);
    scatter1_k<<<2048, 256, 0, stream>>>(x, ea, ei, flag, agg1, E);
    const int nb = (N + 31) / 32;
    gemm1_k<<<nb, 256, 0, stream>>>(agg1, x, W1rel, W1root, b1, h, bnsum, bnsq, N);
    bnfinal_k<<<1, 128, 0, stream>>>(bnsum, bnsq, gamma, beta, bnscale, bnshift, N);
    gemm2_k<<<nb, 256, 0, stream>>>(h, bnscale, bnshift, W2rel, W2root, b2, y2,
                                    (float*)d_out, N);
    scatter2_k<<<2048, 256, 0, stream>>>(y2, ea, ei, flag, (float*)d_out, E);
}

// Round 2
// 222.706 us; speedup vs baseline: 1.6645x; 1.6645x over previous
//
#include <hip/hip_runtime.h>
#include <hip/hip_bf16.h>

// ---------------------------------------------------------------------------
// GCN 2-layer + BN + tanh. Atomic-free aggregation:
//   build dst-bucketed adjacency (CAP=32/row + overflow list) ONCE,
//   then both layers aggregate via gather-SpMM (one wave per dst row).
// Layer-2 GEMM is hoisted before aggregation (matmul commutes w/ segment_sum)
// so the second SpMM moves 32 floats/row-edge instead of 128.
// ---------------------------------------------------------------------------

#define CAP 32
#define OVF_CAP 131072

__device__ __forceinline__ void atomAdd(float* p, float v) { unsafeAtomicAdd(p, v); }

__global__ void detect64_k(const void* __restrict__ ei, int E, int N, int* flag) {
    __shared__ int ok;
    if (threadIdx.x == 0) ok = 1;
    __syncthreads();
    const long long* p = (const long long*)ei;
    int cnt = (E < 1024) ? E : 1024;
    for (int i = threadIdx.x; i < cnt; i += blockDim.x) {
        long long v = p[i];
        if (v < 0 || v >= (long long)N) ok = 0;  // benign race
    }
    __syncthreads();
    if (threadIdx.x == 0) *flag = ok;
}

// Bucket edges by dst: bins[dst*CAP + pos] = {src, w_bits}; overflow -> list.
__global__ __launch_bounds__(256) void fill_k(
    const float* __restrict__ ea, const void* __restrict__ ei,
    const int* __restrict__ flag, int* __restrict__ cnt,
    uint2* __restrict__ bins, int* __restrict__ ovfcnt,
    int4* __restrict__ ovf, int E) {
    int e = blockIdx.x * 256 + threadIdx.x;
    if (e >= E) return;
    const bool is64 = (*flag != 0);
    int src, dst;
    if (is64) {
        const long long* p = (const long long*)ei;
        src = (int)p[e]; dst = (int)p[E + e];
    } else {
        const int* p = (const int*)ei;
        src = p[e]; dst = p[E + e];
    }
    unsigned wb = __float_as_uint(ea[e]);
    int pos = atomicAdd(&cnt[dst], 1);
    if (pos < CAP) {
        bins[(size_t)dst * CAP + pos] = make_uint2((unsigned)src, wb);
    } else {
        int o = atomicAdd(ovfcnt, 1);
        if (o < OVF_CAP) ovf[o] = make_int4(src, dst, (int)wb, 0);
    }
}

// agg[row][0..63] = sum_j w_j * x[src_j][0..63], one wave per row.
__global__ __launch_bounds__(256) void spmm1_k(
    const float* __restrict__ x, const int* __restrict__ cntg,
    const uint2* __restrict__ bins, float* __restrict__ agg, int N) {
    const int lane = threadIdx.x & 63;
    const int row = (blockIdx.x * 256 + threadIdx.x) >> 6;
    if (row >= N) return;
    int cnt = cntg[row]; if (cnt > CAP) cnt = CAP;
    uint2 eg = make_uint2(0u, 0u);
    if (lane < cnt) eg = bins[(size_t)row * CAP + lane];
    float acc = 0.f;
    for (int j = 0; j < cnt; j += 4) {
        int s[4]; float w[4], v[4];
#pragma unroll
        for (int k = 0; k < 4; k++) {
            int idx = j + k;
            bool ok = idx < cnt;
            int ss = __shfl((int)eg.x, idx);
            unsigned wb = (unsigned)__shfl((int)eg.y, idx);
            s[k] = ok ? ss : 0;
            w[k] = ok ? __uint_as_float(wb) : 0.f;
        }
#pragma unroll
        for (int k = 0; k < 4; k++) v[k] = x[(size_t)s[k] * 64 + lane];
#pragma unroll
        for (int k = 0; k < 4; k++) acc = fmaf(w[k], v[k], acc);
    }
    agg[(size_t)row * 64 + lane] = acc;
}

// Overflow edges, layer 1 (runs after spmm1): atomic add.
__global__ __launch_bounds__(256) void ovf1_k(
    const float* __restrict__ x, const int* __restrict__ ovfcnt,
    const int4* __restrict__ ovf, float* __restrict__ agg) {
    int n = *ovfcnt; if (n > OVF_CAP) n = OVF_CAP;
    const int lane = threadIdx.x & 63;
    int wid = (blockIdx.x * 256 + threadIdx.x) >> 6;
    int nw = (gridDim.x * 256) >> 6;
    for (int i = wid; i < n; i += nw) {
        int4 t = ovf[i];
        float w = __uint_as_float((unsigned)t.z);
        atomAdd(&agg[(size_t)t.y * 64 + lane], w * x[(size_t)t.x * 64 + lane]);
    }
}

// h = [agg | x] @ [W1_rel ; W1_root] + b1, fused BN-stat partials.
__global__ __launch_bounds__(256) void gemm1_k(
    const float* __restrict__ agg, const float* __restrict__ x,
    const float* __restrict__ W1rel, const float* __restrict__ W1root,
    const float* __restrict__ b1, float* __restrict__ h,
    float* __restrict__ bnsum, float* __restrict__ bnsq, int N) {
    __shared__ float As[32][128];
    __shared__ float redS[4][128];
    __shared__ float redQ[4][128];
    const int t = threadIdx.x;
    const int row0 = blockIdx.x * 32;

    for (int i = t; i < 32 * 32; i += 256) {
        int r = i >> 5, q = i & 31;
        int rr = row0 + r;
        float4 v = make_float4(0.f, 0.f, 0.f, 0.f);
        if (rr < N) {
            if (q < 16) v = ((const float4*)(agg + (size_t)rr * 64))[q];
            else        v = ((const float4*)(x   + (size_t)rr * 64))[q - 16];
        }
        ((float4*)As[r])[q] = v;
    }
    __syncthreads();

    const int c2 = (t & 63) * 2;
    const int rg = t >> 6;
    float acc[8][2];
#pragma unroll
    for (int r = 0; r < 8; r++) { acc[r][0] = 0.f; acc[r][1] = 0.f; }

#pragma unroll
    for (int half = 0; half < 2; half++) {
        const float* W = half ? W1root : W1rel;
        const int kbase = half * 64;
        for (int kk = 0; kk < 64; kk += 4) {
            float2 wa = *(const float2*)(W + (kk + 0) * 128 + c2);
            float2 wb = *(const float2*)(W + (kk + 1) * 128 + c2);
            float2 wc = *(const float2*)(W + (kk + 2) * 128 + c2);
            float2 wd = *(const float2*)(W + (kk + 3) * 128 + c2);
#pragma unroll
            for (int r = 0; r < 8; r++) {
                const float4 a = *(const float4*)&As[rg * 8 + r][kbase + kk];
                acc[r][0] = fmaf(a.x, wa.x, fmaf(a.y, wb.x, fmaf(a.z, wc.x, fmaf(a.w, wd.x, acc[r][0]))));
                acc[r][1] = fmaf(a.x, wa.y, fmaf(a.y, wb.y, fmaf(a.z, wc.y, fmaf(a.w, wd.y, acc[r][1]))));
            }
        }
    }

    float bc0 = b1[c2], bc1 = b1[c2 + 1];
    float s0 = 0.f, s1 = 0.f, q0 = 0.f, q1 = 0.f;
#pragma unroll
    for (int r = 0; r < 8; r++) {
        int rr = row0 + rg * 8 + r;
        if (rr < N) {
            float v0 = acc[r][0] + bc0;
            float v1 = acc[r][1] + bc1;
            *(float2*)(h + (size_t)rr * 128 + c2) = make_float2(v0, v1);
            s0 += v0; s1 += v1; q0 += v0 * v0; q1 += v1 * v1;
        }
    }
    redS[rg][c2] = s0; redS[rg][c2 + 1] = s1;
    redQ[rg][c2] = q0; redQ[rg][c2 + 1] = q1;
    __syncthreads();
    if (t < 128) {
        float s = redS[0][t] + redS[1][t] + redS[2][t] + redS[3][t];
        float q = redQ[0][t] + redQ[1][t] + redQ[2][t] + redQ[3][t];
        atomAdd(&bnsum[t], s);
        atomAdd(&bnsq[t], q);
    }
}

__global__ void bnfinal_k(const float* __restrict__ bnsum, const float* __restrict__ bnsq,
                          const float* __restrict__ gamma, const float* __restrict__ beta,
                          float* __restrict__ scale, float* __restrict__ shift, int N) {
    int i = threadIdx.x;
    float inv = 1.0f / (float)N;
    float mean = bnsum[i] * inv;
    float var = bnsq[i] * inv - mean * mean;
    if (var < 0.f) var = 0.f;
    float sc = gamma[i] * rsqrtf(var + 1e-5f);
    scale[i] = sc;
    shift[i] = beta[i] - mean * sc;
}

// act = tanh(h*scale+shift); y2 = act@W2_rel ; out = act@W2_root + b2.
__global__ __launch_bounds__(256) void gemm2_k(
    const float* __restrict__ h, const float* __restrict__ scale,
    const float* __restrict__ shift, const float* __restrict__ W2rel,
    const float* __restrict__ W2root, const float* __restrict__ b2,
    float* __restrict__ y2, float* __restrict__ out, int N) {
    __shared__ float As[32][128];
    const int t = threadIdx.x;
    const int row0 = blockIdx.x * 32;

    for (int i = t; i < 32 * 32; i += 256) {
        int r = i >> 5, q = i & 31;
        int rr = row0 + r;
        float4 v = make_float4(0.f, 0.f, 0.f, 0.f);
        if (rr < N) {
            float4 hv = ((const float4*)(h + (size_t)rr * 128))[q];
            float4 sc = ((const float4*)scale)[q];
            float4 sh = ((const float4*)shift)[q];
            v.x = tanhf(fmaf(hv.x, sc.x, sh.x));
            v.y = tanhf(fmaf(hv.y, sc.y, sh.y));
            v.z = tanhf(fmaf(hv.z, sc.z, sh.z));
            v.w = tanhf(fmaf(hv.w, sc.w, sh.w));
        }
        ((float4*)As[r])[q] = v;
    }
    __syncthreads();

    const int c = t & 63;
    const int rg = t >> 6;
    const bool isRel = (c < 32);
    const float* W = isRel ? W2rel : W2root;
    const int cc = isRel ? c : (c - 32);
    float acc[8];
#pragma unroll
    for (int r = 0; r < 8; r++) acc[r] = 0.f;

    for (int k = 0; k < 128; k += 4) {
        float wa = W[(k + 0) * 32 + cc];
        float wb = W[(k + 1) * 32 + cc];
        float wc = W[(k + 2) * 32 + cc];
        float wd = W[(k + 3) * 32 + cc];
#pragma unroll
        for (int r = 0; r < 8; r++) {
            const float4 a = *(const float4*)&As[rg * 8 + r][k];
            acc[r] = fmaf(a.x, wa, fmaf(a.y, wb, fmaf(a.z, wc, fmaf(a.w, wd, acc[r]))));
        }
    }

#pragma unroll
    for (int r = 0; r < 8; r++) {
        int rr = row0 + rg * 8 + r;
        if (rr < N) {
            if (isRel) y2[(size_t)rr * 32 + cc] = acc[r];
            else       out[(size_t)rr * 32 + cc] = acc[r] + b2[cc];
        }
    }
}

// out[row][0..31] += sum_j w_j * y2[src_j][0..31], one wave per row (2 edges/iter
// via half-waves), plain RMW (wave owns the row).
__global__ __launch_bounds__(256) void spmm2_k(
    const float* __restrict__ y2, const int* __restrict__ cntg,
    const uint2* __restrict__ bins, float* __restrict__ out, int N) {
    const int lane = threadIdx.x & 63;
    const int f = lane & 31;
    const int sub = lane >> 5;
    const int row = (blockIdx.x * 256 + threadIdx.x) >> 6;
    if (row >= N) return;
    int cnt = cntg[row]; if (cnt > CAP) cnt = CAP;
    uint2 eg = make_uint2(0u, 0u);
    if (lane < cnt) eg = bins[(size_t)row * CAP + lane];
    float acc = 0.f;
    for (int j = 0; j < cnt; j += 4) {
        int s[2]; float w[2], v[2];
#pragma unroll
        for (int k = 0; k < 2; k++) {
            int idx = j + 2 * k + sub;
            bool ok = idx < cnt;
            int ss = __shfl((int)eg.x, idx);
            unsigned wb = (unsigned)__shfl((int)eg.y, idx);
            s[k] = ok ? ss : 0;
            w[k] = ok ? __uint_as_float(wb) : 0.f;
        }
#pragma unroll
        for (int k = 0; k < 2; k++) v[k] = y2[(size_t)s[k] * 32 + f];
#pragma unroll
        for (int k = 0; k < 2; k++) acc = fmaf(w[k], v[k], acc);
    }
    acc += __shfl_xor(acc, 32);
    if (sub == 0) {
        float* p = &out[(size_t)row * 32 + f];
        *p = *p + acc;
    }
}

// Overflow edges, layer 2 (after spmm2): atomic add into out.
__global__ __launch_bounds__(256) void ovf2_k(
    const float* __restrict__ y2, const int* __restrict__ ovfcnt,
    const int4* __restrict__ ovf, float* __restrict__ out) {
    int n = *ovfcnt; if (n > OVF_CAP) n = OVF_CAP;
    const int lane = threadIdx.x & 63;
    const int f = lane & 31;
    int wid = (blockIdx.x * 256 + threadIdx.x) >> 6;
    int nw = (gridDim.x * 256) >> 6;
    for (int i = wid; i < n; i += nw) {
        int4 t = ovf[i];
        if (lane < 32) {
            float w = __uint_as_float((unsigned)t.z);
            atomAdd(&out[(size_t)t.y * 32 + f], w * y2[(size_t)t.x * 32 + f]);
        }
    }
}

extern "C" void kernel_launch(void* const* d_in, const int* in_sizes, int n_in,
                              void* d_out, int out_size, void* d_ws, size_t ws_size,
                              hipStream_t stream) {
    const float* x      = (const float*)d_in[0];
    const float* ea     = (const float*)d_in[1];
    const float* W1rel  = (const float*)d_in[2];
    const float* b1     = (const float*)d_in[3];
    const float* W1root = (const float*)d_in[4];
    const float* gamma  = (const float*)d_in[5];
    const float* beta   = (const float*)d_in[6];
    const float* W2rel  = (const float*)d_in[7];
    const float* b2     = (const float*)d_in[8];
    const float* W2root = (const float*)d_in[9];
    const void*  ei     = d_in[10];

    const int N = in_sizes[0] / 64;   // 50000
    const int E = in_sizes[1];        // 800000

    char* ws = (char*)d_ws;
    size_t off = 0;
    // --- zero-init region (contiguous) ---
    float* bnsum  = (float*)(ws + off); off += 512;
    float* bnsq   = (float*)(ws + off); off += 512;
    int*   cnt    = (int*)  (ws + off); off += ((size_t)N * 4 + 255) & ~255ull;
    int*   ovfcnt = (int*)  (ws + off); off += 256;
    const size_t zeroBytes = off;
    // --- no-init region ---
    int*   flag    = (int*)  (ws + off); off += 256;
    float* bnscale = (float*)(ws + off); off += 512;
    float* bnshift = (float*)(ws + off); off += 512;
    float* agg1    = (float*)(ws + off); off += (size_t)N * 64 * 4;        // 12.8 MB
    float* h       = (float*)(ws + off); off += (size_t)N * 128 * 4;       // 25.6 MB
    float* y2      = (float*)(ws + off); off += (size_t)N * 32 * 4;        // 6.4 MB
    uint2* bins    = (uint2*)(ws + off); off += (size_t)N * CAP * 8;       // 12.8 MB
    int4*  ovf     = (int4*) (ws + off); off += (size_t)OVF_CAP * 16;      // 2 MB

    hipMemsetAsync(ws, 0, zeroBytes, stream);
    detect64_k<<<1, 256, 0, stream>>>(ei, E, N, flag);
    fill_k<<<(E + 255) / 256, 256, 0, stream>>>(ea, ei, flag, cnt, bins, ovfcnt, ovf, E);
    const int rowBlocks = (N * 64 + 255) / 256;     // one wave per row
    spmm1_k<<<rowBlocks, 256, 0, stream>>>(x, cnt, bins, agg1, N);
    ovf1_k<<<32, 256, 0, stream>>>(x, ovfcnt, ovf, agg1);
    const int nb = (N + 31) / 32;
    gemm1_k<<<nb, 256, 0, stream>>>(agg1, x, W1rel, W1root, b1, h, bnsum, bnsq, N);
    bnfinal_k<<<1, 128, 0, stream>>>(bnsum, bnsq, gamma, beta, bnscale, bnshift, N);
    gemm2_k<<<nb, 256, 0, stream>>>(h, bnscale, bnshift, W2rel, W2root, b2, y2,
                                    (float*)d_out, N);
    spmm2_k<<<rowBlocks, 256, 0, stream>>>(y2, cnt, bins, (float*)d_out, N);
    ovf2_k<<<32, 256, 0, stream>>>(y2, ovfcnt, ovf, (float*)d_out);
}